// Round 1
// baseline (10346.749 us; speedup 1.0000x reference)
//
#include <hip/hip_runtime.h>
#include <math.h>

// Model constants
#define H_    768
#define NH_   12
#define NKV_  4
#define HD_   64
#define IM_   3072
#define IMH_  1536   // IM/2 (MLP processed in two column halves)
#define KCONV 4
#define EPS_  1e-6f
#define B_    2
#define S_    1024
#define BS_   2048   // B*S
#define V_    50304

typedef unsigned short u16;
typedef __bf16 bf16x8 __attribute__((ext_vector_type(8)));
typedef float  f32x4  __attribute__((ext_vector_type(4)));

// ---------------------------------------------------------------------------
// fp32 <-> bf16-pair (hi/lo) helpers.  a ≈ bf2f(hi) + bf2f(lo), |lo| <= 2^-8 |a|
__device__ __forceinline__ u16 f2bf(float f) {
    unsigned u = __float_as_uint(f);
    u += 0x7fffu + ((u >> 16) & 1u);           // round-to-nearest-even
    return (u16)(u >> 16);
}
__device__ __forceinline__ float bf2f(u16 h) {
    return __uint_as_float((unsigned)h << 16);
}
__device__ __forceinline__ void sp_store(u16* __restrict__ hi, u16* __restrict__ lo,
                                         size_t i, float f) {
    u16 h = f2bf(f);
    hi[i] = h;
    lo[i] = f2bf(f - bf2f(h));
}
// global -> LDS direct (16B per lane, dest = base + lane*16)
__device__ __forceinline__ void load_lds16(const void* g, void* l) {
    __builtin_amdgcn_global_load_lds(
        (const __attribute__((address_space(1))) void*)g,
        (__attribute__((address_space(3))) void*)l, 16, 0, 0);
}

// ---------------------------------------------------------------------------
// Embedding lookup: x[bs, :] = embed[tok[bs], :]
__global__ void embed_kernel(const int* __restrict__ tok,
                             const float* __restrict__ emb,
                             float* __restrict__ x) {
    int bs = blockIdx.x;
    int t = threadIdx.x;
    int tk = tok[bs];
    const float* e = emb + (size_t)tk * H_;
    float* xr = x + (size_t)bs * H_;
    xr[t]       = e[t];
    xr[t + 256] = e[t + 256];
    xr[t + 512] = e[t + 512];
}

// ---------------------------------------------------------------------------
// RMSNorm over rows of length 768, output split to bf16 hi/lo (GEMM A operand).
__global__ void rmsnorm768_split(const float* __restrict__ x,
                                 const float* __restrict__ wt,
                                 u16* __restrict__ yh, u16* __restrict__ yl) {
    int row = blockIdx.x;
    int t = threadIdx.x;
    const float* xr = x + (size_t)row * H_;
    float v0 = xr[t], v1 = xr[t + 256], v2 = xr[t + 512];
    __shared__ float red[256];
    red[t] = v0 * v0 + v1 * v1 + v2 * v2;
    __syncthreads();
    for (int o = 128; o > 0; o >>= 1) {
        if (t < o) red[t] += red[t + o];
        __syncthreads();
    }
    float inv = rsqrtf(red[0] / (float)H_ + EPS_);
    size_t base = (size_t)row * H_;
    sp_store(yh, yl, base + t,       v0 * inv * wt[t]);
    sp_store(yh, yl, base + t + 256, v1 * inv * wt[t + 256]);
    sp_store(yh, yl, base + t + 512, v2 * inv * wt[t + 512]);
}

// ---------------------------------------------------------------------------
// RMSNorm over rows of length 64 (per-head q/k norm), in place (fp32).
__global__ void rmsnorm_head(float* __restrict__ x,
                             const float* __restrict__ w, int rows) {
    int lane = threadIdx.x & 63;
    int wv = threadIdx.x >> 6;
    int row = blockIdx.x * 4 + wv;
    if (row >= rows) return;
    float* xr = x + (size_t)row * HD_;
    float v = xr[lane];
    float ss = v * v;
    for (int o = 32; o > 0; o >>= 1) ss += __shfl_xor(ss, o);
    float inv = rsqrtf(ss / (float)HD_ + EPS_);
    xr[lane] = v * inv * w[lane];
}

// ---------------------------------------------------------------------------
// RoPE in place on [B,S,nh,64].
__global__ void rope_kernel(float* __restrict__ x, int nh) {
    size_t idx = (size_t)blockIdx.x * 256 + threadIdx.x;
    size_t total = (size_t)BS_ * nh * 32;
    if (idx >= total) return;
    int d = (int)(idx & 31);
    size_t rest = idx >> 5;
    int h = (int)(rest % nh);
    size_t bs = rest / nh;
    int s = (int)(bs & (S_ - 1));
    float inv = powf(10000.0f, -(float)(2 * d) / (float)HD_);
    float ang = (float)s * inv;
    float c = cosf(ang), sn = sinf(ang);
    float* p = x + (bs * nh + h) * HD_;
    float x0 = p[d], x1 = p[d + 32];
    p[d]      = x0 * c - x1 * sn;
    p[d + 32] = x1 * c + x0 * sn;
}

// ---------------------------------------------------------------------------
// Fused causal GQA attention, one block (256 thr) per query row.
// Output written split (bf16 hi/lo) — it is the A operand of the o-proj GEMM.
__global__ __launch_bounds__(256) void attn_kernel(
        const float* __restrict__ q, const float* __restrict__ k,
        const float* __restrict__ v, u16* __restrict__ oh, u16* __restrict__ ol) {
    int row = blockIdx.x;               // b*NH*S + h*S + i
    int i = row & (S_ - 1);
    int h = (row >> 10) % NH_;
    int b = row / (S_ * NH_);
    int kh = h / (NH_ / NKV_);
    int t = threadIdx.x;

    __shared__ float qs[HD_];
    __shared__ float sc[S_];
    __shared__ float red[256];

    const float* qrow = q + ((size_t)(b * S_ + i) * NH_ + h) * HD_;
    if (t < HD_) qs[t] = qrow[t];
    __syncthreads();

    for (int j = t; j <= i; j += 256) {
        const float4* k4 = (const float4*)(k + ((size_t)(b * S_ + j) * NKV_ + kh) * HD_);
        float s = 0.f;
#pragma unroll
        for (int d4 = 0; d4 < HD_ / 4; d4++) {
            float4 kv = k4[d4];
            s += qs[4 * d4 + 0] * kv.x + qs[4 * d4 + 1] * kv.y +
                 qs[4 * d4 + 2] * kv.z + qs[4 * d4 + 3] * kv.w;
        }
        sc[j] = s * 0.125f;
    }
    __syncthreads();

    float m = -1e30f;
    for (int j = t; j <= i; j += 256) m = fmaxf(m, sc[j]);
    red[t] = m; __syncthreads();
    for (int off = 128; off > 0; off >>= 1) {
        if (t < off) red[t] = fmaxf(red[t], red[t + off]);
        __syncthreads();
    }
    m = red[0];
    __syncthreads();

    float ssum = 0.f;
    for (int j = t; j <= i; j += 256) {
        float e = expf(sc[j] - m);
        sc[j] = e;
        ssum += e;
    }
    red[t] = ssum; __syncthreads();
    for (int off = 128; off > 0; off >>= 1) {
        if (t < off) red[t] += red[t + off];
        __syncthreads();
    }
    float inv = 1.0f / red[0];
    __syncthreads();

    int dt = t & 63, g = t >> 6;
    float acc = 0.f;
    for (int j = g; j <= i; j += 4) {
        acc += sc[j] * v[((size_t)(b * S_ + j) * NKV_ + kh) * HD_ + dt];
    }
    red[t] = acc; __syncthreads();
    if (g == 0) {
        float r = (red[dt] + red[64 + dt] + red[128 + dt] + red[192 + dt]) * inv;
        sp_store(oh, ol, ((size_t)(b * S_ + i) * NH_ + h) * HD_ + dt, r);
    }
}

// ---------------------------------------------------------------------------
// Causal depthwise conv gating; output split (A operand of out_w GEMM).
__global__ void conv_kernel(const float* __restrict__ bcx,
                            const float* __restrict__ cw,
                            const float* __restrict__ cb,
                            u16* __restrict__ yh, u16* __restrict__ yl) {
    size_t idx = (size_t)blockIdx.x * 256 + threadIdx.x;
    if (idx >= (size_t)BS_ * H_) return;
    int c = (int)(idx % H_);
    size_t bs = idx / H_;
    int s = (int)(bs & (S_ - 1));
    int b = (int)(bs >> 10);
    const float* base = bcx + (size_t)b * S_ * (3 * H_);
    float conv = cb[c];
#pragma unroll
    for (int t = 0; t < KCONV; t++) {
        int sp = s - (KCONV - 1) + t;
        if (sp >= 0) {
            float Bg = base[(size_t)sp * (3 * H_) + c];
            float xg = base[(size_t)sp * (3 * H_) + 2 * H_ + c];
            conv += cw[c * KCONV + t] * (Bg * xg);
        }
    }
    float Cg = base[(size_t)s * (3 * H_) + H_ + c];
    sp_store(yh, yl, idx, Cg * conv);
}

// ---------------------------------------------------------------------------
// Split a (rows x cols) fp32 matrix (row stride ld) into packed bf16 hi/lo
// (row stride cols).  Used for weights (per-GEMM) before each MFMA GEMM.
__global__ void wsplit(const float* __restrict__ in, u16* __restrict__ hi,
                       u16* __restrict__ lo, int cols4, int ld) {
    int c4 = blockIdx.x * 256 + threadIdx.x;
    if (c4 >= cols4) return;
    int r = blockIdx.y;
    float4 f = *(const float4*)(in + (size_t)r * ld + (size_t)c4 * 4);
    u16 h0 = f2bf(f.x), h1 = f2bf(f.y), h2 = f2bf(f.z), h3 = f2bf(f.w);
    ushort4 hv = make_ushort4(h0, h1, h2, h3);
    ushort4 lv = make_ushort4(f2bf(f.x - bf2f(h0)), f2bf(f.y - bf2f(h1)),
                              f2bf(f.z - bf2f(h2)), f2bf(f.w - bf2f(h3)));
    size_t o = ((size_t)r * cols4 + c4) * 4;
    *(ushort4*)(hi + o) = hv;
    *(ushort4*)(lo + o) = lv;
}

// ---------------------------------------------------------------------------
// bf16x3 split MFMA GEMM:  C[M,N] = A[M,K] * W[N,K]^T  in ~fp32 precision.
// A,W given as bf16 hi/lo pairs.  128x128 tile, BK=32, 4 waves, m97 structure:
// global_load_lds(16B) staging with chunk-XOR swizzle; 48 MFMA / K-tile / wave.
// Epilogue modes: 0 = fp32 out (+bias)(+resid); 1 = split out to (Sh,Sl);
//                 2 = o = silu(S)*acc, split out to (Sh,Sl)  [MLP up fusion].
__global__ __launch_bounds__(256) void gemm_bf16x3(
        const u16* __restrict__ Ah, const u16* __restrict__ Al,
        const u16* __restrict__ Wh, const u16* __restrict__ Wl,
        const float* __restrict__ bias, const float* __restrict__ resid,
        float* __restrict__ C, u16* __restrict__ Sh, u16* __restrict__ Sl,
        int K, int ldc, int mode) {
    __shared__ u16 AsH[4096], AsL[4096], WsH[4096], WsL[4096];   // [128][32]
    int tid = threadIdx.x;
    int l = tid & 63, w = tid >> 6;
    int bm = blockIdx.y << 7, bn = blockIdx.x << 7;

    // --- staging addresses (k0-invariant, bytes) ---------------------------
    // wave w stages rows [w*32, w*32+32) of each of the 4 LDS arrays.
    // lane i covers (row = rowbase + (i>>2), chunk = i&3); source chunk is
    // XOR-swizzled: chunk_src = chunk ^ ((row>>1)&3)  (involution).
    int r0 = (w << 5) + (l >> 2);
    int r1 = r0 + 16;
    int c0 = ((l & 3) ^ ((r0 >> 1) & 3)) << 3;   // shorts
    int c1 = ((l & 3) ^ ((r1 >> 1) & 3)) << 3;
    size_t ga0 = ((size_t)(bm + r0) * K + c0) * 2;
    size_t ga1 = ((size_t)(bm + r1) * K + c1) * 2;
    size_t gw0 = ((size_t)(bn + r0) * K + c0) * 2;
    size_t gw1 = ((size_t)(bn + r1) * K + c1) * 2;
    const char* pAh = (const char*)Ah;
    const char* pAl = (const char*)Al;
    const char* pWh = (const char*)Wh;
    const char* pWl = (const char*)Wl;
    int lo0 = w << 10;          // LDS short-offset of rowbase r0
    int lo1 = lo0 + 512;        // rowbase r1

    // --- fragment read offsets (shorts) ------------------------------------
    int lr = l & 15, g = l >> 4;
    int fc = (g ^ ((lr >> 1) & 3)) << 3;         // swizzled chunk on read side
    int wr = w >> 1, wc = w & 1;
    int sA = ((wr << 6) + lr) * 32 + fc;         // + m*512
    int sW = ((wc << 6) + lr) * 32 + fc;         // + n*512

    f32x4 acc[4][4] = {};

    for (int k0 = 0; k0 < K; k0 += 32) {
        size_t kb = (size_t)k0 << 1;
        load_lds16(pAh + ga0 + kb, &AsH[lo0]);
        load_lds16(pAh + ga1 + kb, &AsH[lo1]);
        load_lds16(pAl + ga0 + kb, &AsL[lo0]);
        load_lds16(pAl + ga1 + kb, &AsL[lo1]);
        load_lds16(pWh + gw0 + kb, &WsH[lo0]);
        load_lds16(pWh + gw1 + kb, &WsH[lo1]);
        load_lds16(pWl + gw0 + kb, &WsL[lo0]);
        load_lds16(pWl + gw1 + kb, &WsL[lo1]);
        __syncthreads();

        bf16x8 fah[4], fal[4], fwh[4], fwl[4];
#pragma unroll
        for (int m = 0; m < 4; m++) {
            fah[m] = *(const bf16x8*)&AsH[sA + m * 512];
            fal[m] = *(const bf16x8*)&AsL[sA + m * 512];
            fwh[m] = *(const bf16x8*)&WsH[sW + m * 512];
            fwl[m] = *(const bf16x8*)&WsL[sW + m * 512];
        }
#pragma unroll
        for (int m = 0; m < 4; m++)
#pragma unroll
            for (int n = 0; n < 4; n++) {
                f32x4 a = acc[m][n];
                a = __builtin_amdgcn_mfma_f32_16x16x32_bf16(fah[m], fwh[n], a, 0, 0, 0);
                a = __builtin_amdgcn_mfma_f32_16x16x32_bf16(fal[m], fwh[n], a, 0, 0, 0);
                a = __builtin_amdgcn_mfma_f32_16x16x32_bf16(fah[m], fwl[n], a, 0, 0, 0);
                acc[m][n] = a;
            }
        __syncthreads();
    }

    // --- epilogue: C/D mapping col = lane&15, row = (lane>>4)*4 + reg ------
    int gnb = bn + (wc << 6) + lr;
    int gmb = bm + (wr << 6) + (g << 2);
#pragma unroll
    for (int m = 0; m < 4; m++) {
#pragma unroll
        for (int n = 0; n < 4; n++) {
            int gn = gnb + n * 16;
            float badd = bias ? bias[gn] : 0.0f;
#pragma unroll
            for (int r = 0; r < 4; r++) {
                int gm = gmb + m * 16 + r;
                size_t idx = (size_t)gm * ldc + gn;
                float v = acc[m][n][r] + badd;
                if (mode == 0) {
                    if (resid) v += resid[idx];
                    C[idx] = v;
                } else if (mode == 1) {
                    sp_store(Sh, Sl, idx, v);
                } else {
                    float gt = bf2f(Sh[idx]) + bf2f(Sl[idx]);   // gate (fp32 recon)
                    float o = gt / (1.0f + expf(-gt)) * v;      // silu(gate)*up
                    sp_store(Sh, Sl, idx, o);
                }
            }
        }
    }
}

// ---------------------------------------------------------------------------
static inline void wsplit_launch(const float* wsrc, int rows, int cols, int ld,
                                 u16* hi, u16* lo, hipStream_t st) {
    int cols4 = cols / 4;
    dim3 g((cols4 + 255) / 256, rows);
    wsplit<<<g, 256, 0, st>>>(wsrc, hi, lo, cols4, ld);
}

static inline void gemm3(const u16* Ah, const u16* Al, const u16* Wh, const u16* Wl,
                         const float* bias, const float* resid, float* C,
                         u16* Sh, u16* Sl, int M, int N, int K, int ldc, int mode,
                         hipStream_t st) {
    dim3 grid(N / 128, M / 128);
    gemm_bf16x3<<<grid, 256, 0, st>>>(Ah, Al, Wh, Wl, bias, resid, C, Sh, Sl, K, ldc, mode);
}

extern "C" void kernel_launch(void* const* d_in, const int* in_sizes, int n_in,
                              void* d_out, int out_size, void* d_ws, size_t ws_size,
                              hipStream_t stream) {
    const int*   tokens  = (const int*)d_in[0];
    const float* embed   = (const float*)d_in[1];
    const float* qw      = (const float*)d_in[2];
    const float* kw      = (const float*)d_in[3];
    const float* vw      = (const float*)d_in[4];
    const float* ow      = (const float*)d_in[5];
    const float* qln     = (const float*)d_in[6];
    const float* kln     = (const float*)d_in[7];
    const float* a_gate  = (const float*)d_in[8];
    const float* a_up    = (const float*)d_in[9];
    const float* a_down  = (const float*)d_in[10];
    const float* a_ln1   = (const float*)d_in[11];
    const float* a_ln2   = (const float*)d_in[12];
    const float* conv_w  = (const float*)d_in[13];
    const float* conv_b  = (const float*)d_in[14];
    const float* in_w    = (const float*)d_in[15];
    const float* in_b    = (const float*)d_in[16];
    const float* out_w   = (const float*)d_in[17];
    const float* out_b   = (const float*)d_in[18];
    const float* c_gate  = (const float*)d_in[19];
    const float* c_up    = (const float*)d_in[20];
    const float* c_down  = (const float*)d_in[21];
    const float* c_ln1   = (const float*)d_in[22];
    const float* c_ln2   = (const float*)d_in[23];
    const float* fin_ln  = (const float*)d_in[24];
    const float* lm_head = (const float*)d_in[25];

    // workspace layout (51 MB total, within the 62.9 MB the previous kernel used):
    //  x  : BS*H fp32 (residual stream)
    //  s1 : BS*3H fp32 (q|k|v pack, or conv bcx)
    //  Hh/Hl : BS*H bf16 split (rmsnorm out / attn out / conv out — GEMM A)
    //  Gh/Gl : BS*IMH bf16 split (gate -> silu*up, per MLP half — GEMM A)
    //  Wh/Wl : 3072*768 bf16 split (per-GEMM weight staging, double use)
    float* x  = (float*)d_ws;
    float* s1 = x + (size_t)BS_ * H_;
    u16* Hh = (u16*)(s1 + (size_t)BS_ * 3 * H_);
    u16* Hl = Hh + (size_t)BS_ * H_;
    u16* Gh = Hl + (size_t)BS_ * H_;
    u16* Gl = Gh + (size_t)BS_ * IMH_;
    u16* Wh = Gl + (size_t)BS_ * IMH_;
    u16* Wl = Wh + (size_t)3072 * 768;

    embed_kernel<<<BS_, 256, 0, stream>>>(tokens, embed, x);

    int ai = 0, ci = 0;
    for (int l = 0; l < 12; l++) {
        bool full = (l == 2 || l == 5 || l == 8 || l == 11);
        const float* gate_w; const float* up_w; const float* down_w;
        const float* ln2;
        if (full) {
            rmsnorm768_split<<<BS_, 256, 0, stream>>>(x, a_ln1 + (size_t)ai * H_, Hh, Hl);
            float* q = s1;
            float* k = s1 + (size_t)BS_ * H_;
            float* v = k + (size_t)BS_ * (NKV_ * HD_);
            wsplit_launch(qw + (size_t)ai * H_ * H_, H_, H_, H_, Wh, Wl, stream);
            gemm3(Hh, Hl, Wh, Wl, nullptr, nullptr, q, nullptr, nullptr,
                  BS_, H_, H_, H_, 0, stream);
            wsplit_launch(kw + (size_t)ai * NKV_ * HD_ * H_, NKV_ * HD_, H_, H_, Wh, Wl, stream);
            gemm3(Hh, Hl, Wh, Wl, nullptr, nullptr, k, nullptr, nullptr,
                  BS_, NKV_ * HD_, H_, NKV_ * HD_, 0, stream);
            wsplit_launch(vw + (size_t)ai * NKV_ * HD_ * H_, NKV_ * HD_, H_, H_, Wh, Wl, stream);
            gemm3(Hh, Hl, Wh, Wl, nullptr, nullptr, v, nullptr, nullptr,
                  BS_, NKV_ * HD_, H_, NKV_ * HD_, 0, stream);
            rmsnorm_head<<<(BS_ * NH_) / 4, 256, 0, stream>>>(q, qln + (size_t)ai * HD_, BS_ * NH_);
            rmsnorm_head<<<(BS_ * NKV_) / 4, 256, 0, stream>>>(k, kln + (size_t)ai * HD_, BS_ * NKV_);
            rope_kernel<<<(BS_ * NH_ * 32) / 256, 256, 0, stream>>>(q, NH_);
            rope_kernel<<<(BS_ * NKV_ * 32) / 256, 256, 0, stream>>>(k, NKV_);
            attn_kernel<<<B_ * NH_ * S_, 256, 0, stream>>>(q, k, v, Hh, Hl);
            wsplit_launch(ow + (size_t)ai * H_ * H_, H_, H_, H_, Wh, Wl, stream);
            gemm3(Hh, Hl, Wh, Wl, nullptr, x, x, nullptr, nullptr,
                  BS_, H_, H_, H_, 0, stream);
            gate_w = a_gate + (size_t)ai * IM_ * H_;
            up_w   = a_up   + (size_t)ai * IM_ * H_;
            down_w = a_down + (size_t)ai * H_ * IM_;
            ln2    = a_ln2  + (size_t)ai * H_;
            ai++;
        } else {
            rmsnorm768_split<<<BS_, 256, 0, stream>>>(x, c_ln1 + (size_t)ci * H_, Hh, Hl);
            wsplit_launch(in_w + (size_t)ci * 3 * H_ * H_, 3 * H_, H_, H_, Wh, Wl, stream);
            gemm3(Hh, Hl, Wh, Wl, in_b + (size_t)ci * 3 * H_, nullptr, s1, nullptr, nullptr,
                  BS_, 3 * H_, H_, 3 * H_, 0, stream);
            conv_kernel<<<(BS_ * H_) / 256, 256, 0, stream>>>(
                s1, conv_w + (size_t)ci * H_ * KCONV, conv_b + (size_t)ci * H_, Hh, Hl);
            wsplit_launch(out_w + (size_t)ci * H_ * H_, H_, H_, H_, Wh, Wl, stream);
            gemm3(Hh, Hl, Wh, Wl, out_b + (size_t)ci * H_, x, x, nullptr, nullptr,
                  BS_, H_, H_, H_, 0, stream);
            gate_w = c_gate + (size_t)ci * IM_ * H_;
            up_w   = c_up   + (size_t)ci * IM_ * H_;
            down_w = c_down + (size_t)ci * H_ * IM_;
            ln2    = c_ln2  + (size_t)ci * H_;
            ci++;
        }
        // ---- MLP, processed in two IM/2 column halves ----
        rmsnorm768_split<<<BS_, 256, 0, stream>>>(x, ln2, Hh, Hl);
        for (int hf = 0; hf < 2; hf++) {
            // gate half -> split into G
            wsplit_launch(gate_w + (size_t)hf * IMH_ * H_, IMH_, H_, H_, Wh, Wl, stream);
            gemm3(Hh, Hl, Wh, Wl, nullptr, nullptr, nullptr, Gh, Gl,
                  BS_, IMH_, H_, IMH_, 1, stream);
            // up half, fused silu(gate)*up -> split into G
            wsplit_launch(up_w + (size_t)hf * IMH_ * H_, IMH_, H_, H_, Wh, Wl, stream);
            gemm3(Hh, Hl, Wh, Wl, nullptr, nullptr, nullptr, Gh, Gl,
                  BS_, IMH_, H_, IMH_, 2, stream);
            // down half (K = IMH columns of down), accumulate into x
            wsplit_launch(down_w + (size_t)hf * IMH_, H_, IMH_, IM_, Wh, Wl, stream);
            gemm3(Gh, Gl, Wh, Wl, nullptr, x, x, nullptr, nullptr,
                  BS_, H_, IMH_, H_, 0, stream);
        }
    }

    rmsnorm768_split<<<BS_, 256, 0, stream>>>(x, fin_ln, Hh, Hl);
    // lm_head in N-chunks of 3072 (16 full + one 1152 remainder)
    for (int off = 0; off < V_; off += 3072) {
        int nc = (V_ - off < 3072) ? (V_ - off) : 3072;
        wsplit_launch(lm_head + (size_t)off * H_, nc, H_, H_, Wh, Wl, stream);
        gemm3(Hh, Hl, Wh, Wl, nullptr, nullptr, (float*)d_out + off, nullptr, nullptr,
              BS_, nc, H_, V_, 0, stream);
    }
}

// Round 5
// 8293.844 us; speedup vs baseline: 1.2475x; 1.2475x over previous
//
#include <hip/hip_runtime.h>
#include <math.h>

// Model constants
#define H_    768
#define NH_   12
#define NKV_  4
#define HD_   64
#define IM_   3072
#define KCONV 4
#define EPS_  1e-6f
#define B_    2
#define S_    1024
#define BS_   2048   // B*S
#define V_    50304
#define QKVS  1280   // fused q|k|v row stride (768+256+256)

typedef unsigned short u16;
typedef unsigned int   u32;
typedef __bf16 bf16x8 __attribute__((ext_vector_type(8)));
typedef float  f32x4  __attribute__((ext_vector_type(4)));

// ---------------------------------------------------------------------------
// fp32 <-> bf16-pair (hi/lo) helpers.  a ~= bf2f(hi) + bf2f(lo)
__device__ __forceinline__ u16 f2bf(float f) {
    u32 u = __float_as_uint(f);
    u += 0x7fffu + ((u >> 16) & 1u);           // round-to-nearest-even
    return (u16)(u >> 16);
}
__device__ __forceinline__ float bf2f(u16 h) {
    return __uint_as_float((u32)h << 16);
}
__device__ __forceinline__ void sp_store(u16* __restrict__ hi, u16* __restrict__ lo,
                                         size_t i, float f) {
    u16 h = f2bf(f);
    hi[i] = h;
    lo[i] = f2bf(f - bf2f(h));
}
// global -> LDS direct (16B per lane, dest = base + lane*16)
__device__ __forceinline__ void load_lds16(const void* g, void* l) {
    __builtin_amdgcn_global_load_lds(
        (const __attribute__((address_space(1))) void*)g,
        (__attribute__((address_space(3))) void*)l, 16, 0, 0);
}

// ---------------------------------------------------------------------------
__global__ void embed_kernel(const int* __restrict__ tok,
                             const float* __restrict__ emb,
                             float* __restrict__ x) {
    int bs = blockIdx.x;
    int t = threadIdx.x;
    int tk = tok[bs];
    const float* e = emb + (size_t)tk * H_;
    float* xr = x + (size_t)bs * H_;
    xr[t]       = e[t];
    xr[t + 256] = e[t + 256];
    xr[t + 512] = e[t + 512];
}

// ---------------------------------------------------------------------------
// RMSNorm over rows of length 768, output split to bf16 hi/lo (GEMM A operand).
__global__ void rmsnorm768_split(const float* __restrict__ x,
                                 const float* __restrict__ wt,
                                 u16* __restrict__ yh, u16* __restrict__ yl) {
    int row = blockIdx.x;
    int t = threadIdx.x;
    const float* xr = x + (size_t)row * H_;
    float v0 = xr[t], v1 = xr[t + 256], v2 = xr[t + 512];
    __shared__ float red[256];
    red[t] = v0 * v0 + v1 * v1 + v2 * v2;
    __syncthreads();
    for (int o = 128; o > 0; o >>= 1) {
        if (t < o) red[t] += red[t + o];
        __syncthreads();
    }
    float inv = rsqrtf(red[0] / (float)H_ + EPS_);
    size_t base = (size_t)row * H_;
    sp_store(yh, yl, base + t,       v0 * inv * wt[t]);
    sp_store(yh, yl, base + t + 256, v1 * inv * wt[t + 256]);
    sp_store(yh, yl, base + t + 512, v2 * inv * wt[t + 512]);
}

// ---------------------------------------------------------------------------
// RMSNorm over rows of length 64 (per-head q/k norm), in place, strided rows.
__global__ void rmsnorm_head(float* __restrict__ x,
                             const float* __restrict__ w, int rows, int nh,
                             int stride) {
    int lane = threadIdx.x & 63;
    int wv = threadIdx.x >> 6;
    int row = blockIdx.x * 4 + wv;
    if (row >= rows) return;
    int bs = row / nh, h = row % nh;
    float* xr = x + (size_t)bs * stride + h * HD_;
    float v = xr[lane];
    float ss = v * v;
    for (int o = 32; o > 0; o >>= 1) ss += __shfl_xor(ss, o);
    float inv = rsqrtf(ss / (float)HD_ + EPS_);
    xr[lane] = v * inv * w[lane];
}

// ---------------------------------------------------------------------------
// RoPE in place on [B,S,nh,64] rows embedded at the given row stride.
__global__ void rope_kernel(float* __restrict__ x, int nh, int stride) {
    size_t idx = (size_t)blockIdx.x * 256 + threadIdx.x;
    size_t total = (size_t)BS_ * nh * 32;
    if (idx >= total) return;
    int d = (int)(idx & 31);
    size_t rest = idx >> 5;
    int h = (int)(rest % nh);
    size_t bs = rest / nh;
    int s = (int)(bs & (S_ - 1));
    // 10000^(-2d/64) = exp2(-d * log2(10000)/32)
    float inv = exp2f((float)d * -0.41524101186092f);
    float ang = (float)s * inv;
    float c = cosf(ang), sn = sinf(ang);
    float* p = x + bs * stride + h * HD_;
    float x0 = p[d], x1 = p[d + 32];
    p[d]      = x0 * c - x1 * sn;
    p[d + 32] = x1 * c + x0 * sn;
}

// ---------------------------------------------------------------------------
// Fused causal GQA attention on the packed q|k|v buffer (stride QKVS).
// One block (256 thr) per query row; output split bf16 hi/lo (o-proj A).
__global__ __launch_bounds__(256) void attn_kernel(
        const float* __restrict__ qkv, u16* __restrict__ oh, u16* __restrict__ ol) {
    int row = blockIdx.x;               // b*NH*S + h*S + i
    int i = row & (S_ - 1);
    int h = (row >> 10) % NH_;
    int b = row / (S_ * NH_);
    int kh = h / (NH_ / NKV_);
    int t = threadIdx.x;

    __shared__ float qs[HD_];
    __shared__ float sc[S_];
    __shared__ float red[256];

    const float* qrow = qkv + (size_t)(b * S_ + i) * QKVS + h * HD_;
    if (t < HD_) qs[t] = qrow[t];
    __syncthreads();

    const float* kbase = qkv + 768 + kh * HD_;
    const float* vbase = qkv + 1024 + kh * HD_;

    for (int j = t; j <= i; j += 256) {
        const float4* k4 = (const float4*)(kbase + (size_t)(b * S_ + j) * QKVS);
        float s = 0.f;
#pragma unroll
        for (int d4 = 0; d4 < HD_ / 4; d4++) {
            float4 kv = k4[d4];
            s += qs[4 * d4 + 0] * kv.x + qs[4 * d4 + 1] * kv.y +
                 qs[4 * d4 + 2] * kv.z + qs[4 * d4 + 3] * kv.w;
        }
        sc[j] = s * 0.125f;   // 1/sqrt(64)
    }
    __syncthreads();

    float m = -1e30f;
    for (int j = t; j <= i; j += 256) m = fmaxf(m, sc[j]);
    red[t] = m; __syncthreads();
    for (int off = 128; off > 0; off >>= 1) {
        if (t < off) red[t] = fmaxf(red[t], red[t + off]);
        __syncthreads();
    }
    m = red[0];
    __syncthreads();

    float ssum = 0.f;
    for (int j = t; j <= i; j += 256) {
        float e = expf(sc[j] - m);
        sc[j] = e;
        ssum += e;
    }
    red[t] = ssum; __syncthreads();
    for (int off = 128; off > 0; off >>= 1) {
        if (t < off) red[t] += red[t + off];
        __syncthreads();
    }
    float inv = 1.0f / red[0];
    __syncthreads();

    int dt = t & 63, g = t >> 6;
    float acc = 0.f;
    for (int j = g; j <= i; j += 4) {
        acc += sc[j] * vbase[(size_t)(b * S_ + j) * QKVS + dt];
    }
    red[t] = acc; __syncthreads();
    if (g == 0) {
        float r = (red[dt] + red[64 + dt] + red[128 + dt] + red[192 + dt]) * inv;
        sp_store(oh, ol, ((size_t)(b * S_ + i) * NH_ + h) * HD_ + dt, r);
    }
}

// ---------------------------------------------------------------------------
// Causal depthwise conv gating; output split (A operand of out_w GEMM).
__global__ void conv_kernel(const float* __restrict__ bcx,
                            const float* __restrict__ cw,
                            const float* __restrict__ cb,
                            u16* __restrict__ yh, u16* __restrict__ yl) {
    size_t idx = (size_t)blockIdx.x * 256 + threadIdx.x;
    if (idx >= (size_t)BS_ * H_) return;
    int c = (int)(idx % H_);
    size_t bs = idx / H_;
    int s = (int)(bs & (S_ - 1));
    int b = (int)(bs >> 10);
    const float* base = bcx + (size_t)b * S_ * (3 * H_);
    float conv = cb[c];
#pragma unroll
    for (int t = 0; t < KCONV; t++) {
        int sp = s - (KCONV - 1) + t;
        if (sp >= 0) {
            float Bg = base[(size_t)sp * (3 * H_) + c];
            float xg = base[(size_t)sp * (3 * H_) + 2 * H_ + c];
            conv += cw[c * KCONV + t] * (Bg * xg);
        }
    }
    float Cg = base[(size_t)s * (3 * H_) + H_ + c];
    sp_store(yh, yl, idx, Cg * conv);
}

// ---------------------------------------------------------------------------
// bf16x3 split MFMA GEMM:  C[M,N] = A[M,K] * W[N,K]^T  in ~fp32 precision.
// A given as bf16 hi/lo pairs (producer-split); W given as raw fp32 and split
// in-kernel at fragment-read time (RNE hi via round-add, lo = a - hi, trunc).
// 128x128 tile, BK=32, 4 waves; global_load_lds(16B) staging, XOR-swizzled.
// QKV fusion: if Wk != null, blocks bx>=6 use Wk (k) / bx>=8 use Wv (v).
// kSplit: blockIdx.z selects a K-range (used with mode 3).
// Modes: 0 = C=acc(+bias)(+resid); 1 = split-store to (Sh,Sl);
//        2 = silu(S)*acc, split-store;  3 = atomicAdd into C (+bias if k0==0).
__global__ __launch_bounds__(256) void gemm_bf16x3(
        const u16* __restrict__ Ah, const u16* __restrict__ Al,
        const float* __restrict__ W, const float* __restrict__ Wk,
        const float* __restrict__ Wv,
        const float* __restrict__ bias, const float* __restrict__ resid,
        float* __restrict__ C, u16* __restrict__ Sh, u16* __restrict__ Sl,
        int K, int kSplit, int ldc, int mode) {
    __shared__ u16 AsH[4096], AsL[4096];     // [128][32] bf16 hi/lo
    __shared__ float WsF[4096];              // [128][32] fp32
    int tid = threadIdx.x;
    int l = tid & 63, w = tid >> 6;
    int bx = blockIdx.x;
    int bm = blockIdx.y << 7, bn = bx << 7;

    // QKV fused-weight select (q: tiles 0-5, k: 6-7, v: 8-9)
    const float* Wsel = W;
    int bnW = bn;
    if (Wk) {
        if (bx >= 8)      { Wsel = Wv; bnW = bn - 1024; }
        else if (bx >= 6) { Wsel = Wk; bnW = bn - 768; }
    }

    int kLen = K / kSplit;
    int kBegin = blockIdx.z * kLen;
    int kEnd = kBegin + kLen;

    // --- A staging (verified r1 layout): lane -> (row w*32+(l>>2) [+16], chunk l&3),
    //     source chunk XOR-swizzled by (row>>1)&3; LDS linear in lane. ---------
    int ar0 = (w << 5) + (l >> 2);
    int ar1 = ar0 + 16;
    int ac0 = ((l & 3) ^ ((ar0 >> 1) & 3)) << 3;   // shorts
    int ac1 = ((l & 3) ^ ((ar1 >> 1) & 3)) << 3;
    const char* pAh = (const char*)Ah;
    const char* pAl = (const char*)Al;
    size_t ga0 = ((size_t)(bm + ar0) * K + ac0) * 2;
    size_t ga1 = ((size_t)(bm + ar1) * K + ac1) * 2;
    // --- W staging (fp32): lane -> (row w*32+(l>>3) [+8k], chunkpos l&7),
    //     source chunk = (l&7) ^ (l>>3)  (row&7 == l>>3 at every sub-block). --
    int wr0 = (w << 5) + (l >> 3);
    int wcs = ((l & 7) ^ (l >> 3)) << 2;           // floats
    const char* pW = (const char*)Wsel;
    size_t gw0 = ((size_t)(bnW + wr0) * K + wcs) * 4;
    size_t rowstep = (size_t)8 * K * 4;

    int aLo = w << 10;    // shorts: wave w covers rows [w*32, w*32+32)
    int wLo = w << 10;    // floats: 32 rows * 32 floats

    // --- fragment offsets -------------------------------------------------
    int lr = l & 15, g = l >> 4;
    int wr = w >> 1, wc = w & 1;
    int sA = ((wr << 6) + lr) * 32 + ((g ^ ((lr >> 1) & 3)) << 3);   // shorts
    int sW = ((wc << 6) + lr) * 32;                                  // floats
    int p0 = (((2 * g) ^ (lr & 7)) << 2);        // float offs of cols 8g..8g+3
    int p1 = (((2 * g + 1) ^ (lr & 7)) << 2);    // float offs of cols 8g+4..8g+7

    f32x4 acc[4][4] = {};

    for (int kt = kBegin; kt < kEnd; kt += 32) {
        size_t kbA = (size_t)kt * 2, kbW = (size_t)kt * 4;
        load_lds16(pAh + ga0 + kbA, &AsH[aLo]);
        load_lds16(pAh + ga1 + kbA, &AsH[aLo + 512]);
        load_lds16(pAl + ga0 + kbA, &AsL[aLo]);
        load_lds16(pAl + ga1 + kbA, &AsL[aLo + 512]);
        load_lds16(pW + gw0 + kbW,                &WsF[wLo]);
        load_lds16(pW + gw0 + rowstep + kbW,      &WsF[wLo + 256]);
        load_lds16(pW + gw0 + 2 * rowstep + kbW,  &WsF[wLo + 512]);
        load_lds16(pW + gw0 + 3 * rowstep + kbW,  &WsF[wLo + 768]);
        __syncthreads();

        bf16x8 fah[4], fal[4];
#pragma unroll
        for (int m = 0; m < 4; m++) {
            fah[m] = *(const bf16x8*)&AsH[sA + m * 512];
            fal[m] = *(const bf16x8*)&AsL[sA + m * 512];
        }
#pragma unroll
        for (int n = 0; n < 4; n++) {
            f32x4 wa = *(const f32x4*)&WsF[sW + n * 512 + p0];
            f32x4 wb = *(const f32x4*)&WsF[sW + n * 512 + p1];
            // RNE hi split: ur = u + 0x7fff + ((u>>16)&1); hi = ur>>16;
            // lo = a - as_float(ur & 0xffff0000), packed by truncation.
            union { u32 u[4]; bf16x8 v; } FH, FL;
            u32 u0 = __float_as_uint(wa[0]), u1 = __float_as_uint(wa[1]);
            u32 u2 = __float_as_uint(wa[2]), u3 = __float_as_uint(wa[3]);
            u32 u4 = __float_as_uint(wb[0]), u5 = __float_as_uint(wb[1]);
            u32 u6 = __float_as_uint(wb[2]), u7 = __float_as_uint(wb[3]);
            u32 r0 = u0 + 0x7fffu + ((u0 >> 16) & 1u);
            u32 r1 = u1 + 0x7fffu + ((u1 >> 16) & 1u);
            u32 r2 = u2 + 0x7fffu + ((u2 >> 16) & 1u);
            u32 r3 = u3 + 0x7fffu + ((u3 >> 16) & 1u);
            u32 r4 = u4 + 0x7fffu + ((u4 >> 16) & 1u);
            u32 r5 = u5 + 0x7fffu + ((u5 >> 16) & 1u);
            u32 r6 = u6 + 0x7fffu + ((u6 >> 16) & 1u);
            u32 r7 = u7 + 0x7fffu + ((u7 >> 16) & 1u);
            FH.u[0] = __builtin_amdgcn_perm(r1, r0, 0x07060302u);
            FH.u[1] = __builtin_amdgcn_perm(r3, r2, 0x07060302u);
            FH.u[2] = __builtin_amdgcn_perm(r5, r4, 0x07060302u);
            FH.u[3] = __builtin_amdgcn_perm(r7, r6, 0x07060302u);
            float l0 = wa[0] - __uint_as_float(r0 & 0xffff0000u);
            float l1 = wa[1] - __uint_as_float(r1 & 0xffff0000u);
            float l2 = wa[2] - __uint_as_float(r2 & 0xffff0000u);
            float l3 = wa[3] - __uint_as_float(r3 & 0xffff0000u);
            float l4 = wb[0] - __uint_as_float(r4 & 0xffff0000u);
            float l5 = wb[1] - __uint_as_float(r5 & 0xffff0000u);
            float l6 = wb[2] - __uint_as_float(r6 & 0xffff0000u);
            float l7 = wb[3] - __uint_as_float(r7 & 0xffff0000u);
            FL.u[0] = __builtin_amdgcn_perm(__float_as_uint(l1), __float_as_uint(l0), 0x07060302u);
            FL.u[1] = __builtin_amdgcn_perm(__float_as_uint(l3), __float_as_uint(l2), 0x07060302u);
            FL.u[2] = __builtin_amdgcn_perm(__float_as_uint(l5), __float_as_uint(l4), 0x07060302u);
            FL.u[3] = __builtin_amdgcn_perm(__float_as_uint(l7), __float_as_uint(l6), 0x07060302u);
#pragma unroll
            for (int m = 0; m < 4; m++) {
                f32x4 a = acc[m][n];
                a = __builtin_amdgcn_mfma_f32_16x16x32_bf16(fah[m], FH.v, a, 0, 0, 0);
                a = __builtin_amdgcn_mfma_f32_16x16x32_bf16(fal[m], FH.v, a, 0, 0, 0);
                a = __builtin_amdgcn_mfma_f32_16x16x32_bf16(fah[m], FL.v, a, 0, 0, 0);
                acc[m][n] = a;
            }
        }
        __syncthreads();
    }

    // --- epilogue: C/D mapping col = lane&15, row = (lane>>4)*4 + reg ------
    int gnb = bn + (wc << 6) + lr;
    int gmb = bm + (wr << 6) + (g << 2);
#pragma unroll
    for (int m = 0; m < 4; m++) {
#pragma unroll
        for (int n = 0; n < 4; n++) {
            int gn = gnb + n * 16;
            float badd = bias ? bias[gn] : 0.0f;
#pragma unroll
            for (int r = 0; r < 4; r++) {
                int gm = gmb + m * 16 + r;
                size_t idx = (size_t)gm * ldc + gn;
                float v = acc[m][n][r];
                if (mode == 0) {
                    v += badd;
                    if (resid) v += resid[idx];
                    C[idx] = v;
                } else if (mode == 1) {
                    sp_store(Sh, Sl, idx, v);
                } else if (mode == 2) {
                    float gt = bf2f(Sh[idx]) + bf2f(Sl[idx]);
                    float o = gt / (1.0f + expf(-gt)) * v;
                    sp_store(Sh, Sl, idx, o);
                } else {
                    if (kBegin == 0) v += badd;
                    atomicAdd(&C[idx], v);
                }
            }
        }
    }
}

// ---------------------------------------------------------------------------
static inline void gemm3(const u16* Ah, const u16* Al, const float* W,
                         const float* Wk, const float* Wv,
                         const float* bias, const float* resid, float* C,
                         u16* Sh, u16* Sl, int M, int N, int K, int kSplit,
                         int ldc, int mode, hipStream_t st) {
    dim3 grid(N / 128, M / 128, kSplit);
    gemm_bf16x3<<<grid, 256, 0, st>>>(Ah, Al, W, Wk, Wv, bias, resid, C, Sh, Sl,
                                      K, kSplit, ldc, mode);
}

extern "C" void kernel_launch(void* const* d_in, const int* in_sizes, int n_in,
                              void* d_out, int out_size, void* d_ws, size_t ws_size,
                              hipStream_t stream) {
    const int*   tokens  = (const int*)d_in[0];
    const float* embed   = (const float*)d_in[1];
    const float* qw      = (const float*)d_in[2];
    const float* kw      = (const float*)d_in[3];
    const float* vw      = (const float*)d_in[4];
    const float* ow      = (const float*)d_in[5];
    const float* qln     = (const float*)d_in[6];
    const float* kln     = (const float*)d_in[7];
    const float* a_gate  = (const float*)d_in[8];
    const float* a_up    = (const float*)d_in[9];
    const float* a_down  = (const float*)d_in[10];
    const float* a_ln1   = (const float*)d_in[11];
    const float* a_ln2   = (const float*)d_in[12];
    const float* conv_w  = (const float*)d_in[13];
    const float* conv_b  = (const float*)d_in[14];
    const float* in_w    = (const float*)d_in[15];
    const float* in_b    = (const float*)d_in[16];
    const float* out_w   = (const float*)d_in[17];
    const float* out_b   = (const float*)d_in[18];
    const float* c_gate  = (const float*)d_in[19];
    const float* c_up    = (const float*)d_in[20];
    const float* c_down  = (const float*)d_in[21];
    const float* c_ln1   = (const float*)d_in[22];
    const float* c_ln2   = (const float*)d_in[23];
    const float* fin_ln  = (const float*)d_in[24];
    const float* lm_head = (const float*)d_in[25];

    // workspace (56.7 MB):
    //  x  : BS*H fp32 (residual stream)                        6.3 MB
    //  s1 : BS*3H fp32 (fused q|k|v [BS][1280] or conv bcx)   18.9 MB
    //  Hh/Hl : BS*H bf16 split (ln/attn/conv out — GEMM A)     6.3 MB
    //  Gh/Gl : BS*IM bf16 split (gate -> silu*up — GEMM A)    25.2 MB
    float* x  = (float*)d_ws;
    float* s1 = x + (size_t)BS_ * H_;
    u16* Hh = (u16*)(s1 + (size_t)BS_ * 3 * H_);
    u16* Hl = Hh + (size_t)BS_ * H_;
    u16* Gh = Hl + (size_t)BS_ * H_;
    u16* Gl = Gh + (size_t)BS_ * IM_;

    embed_kernel<<<BS_, 256, 0, stream>>>(tokens, embed, x);

    int ai = 0, ci = 0;
    for (int l = 0; l < 12; l++) {
        bool full = (l == 2 || l == 5 || l == 8 || l == 11);
        const float* gate_w; const float* up_w; const float* down_w;
        const float* ln2;
        if (full) {
            rmsnorm768_split<<<BS_, 256, 0, stream>>>(x, a_ln1 + (size_t)ai * H_, Hh, Hl);
            // fused q|k|v projection -> s1 [BS][1280]
            gemm3(Hh, Hl, qw + (size_t)ai * H_ * H_,
                  kw + (size_t)ai * NKV_ * HD_ * H_,
                  vw + (size_t)ai * NKV_ * HD_ * H_,
                  nullptr, nullptr, s1, nullptr, nullptr,
                  BS_, QKVS, H_, 1, QKVS, 0, stream);
            rmsnorm_head<<<(BS_ * NH_) / 4, 256, 0, stream>>>(
                s1, qln + (size_t)ai * HD_, BS_ * NH_, NH_, QKVS);
            rmsnorm_head<<<(BS_ * NKV_) / 4, 256, 0, stream>>>(
                s1 + 768, kln + (size_t)ai * HD_, BS_ * NKV_, NKV_, QKVS);
            rope_kernel<<<(BS_ * NH_ * 32) / 256, 256, 0, stream>>>(s1, NH_, QKVS);
            rope_kernel<<<(BS_ * NKV_ * 32) / 256, 256, 0, stream>>>(s1 + 768, NKV_, QKVS);
            attn_kernel<<<B_ * NH_ * S_, 256, 0, stream>>>(s1, Hh, Hl);
            gemm3(Hh, Hl, ow + (size_t)ai * H_ * H_, nullptr, nullptr,
                  nullptr, x, x, nullptr, nullptr, BS_, H_, H_, 1, H_, 0, stream);
            gate_w = a_gate + (size_t)ai * IM_ * H_;
            up_w   = a_up   + (size_t)ai * IM_ * H_;
            down_w = a_down + (size_t)ai * H_ * IM_;
            ln2    = a_ln2  + (size_t)ai * H_;
            ai++;
        } else {
            rmsnorm768_split<<<BS_, 256, 0, stream>>>(x, c_ln1 + (size_t)ci * H_, Hh, Hl);
            gemm3(Hh, Hl, in_w + (size_t)ci * 3 * H_ * H_, nullptr, nullptr,
                  in_b + (size_t)ci * 3 * H_, nullptr, s1, nullptr, nullptr,
                  BS_, 3 * H_, H_, 1, 3 * H_, 0, stream);
            conv_kernel<<<(BS_ * H_) / 256, 256, 0, stream>>>(
                s1, conv_w + (size_t)ci * H_ * KCONV, conv_b + (size_t)ci * H_, Hh, Hl);
            gemm3(Hh, Hl, out_w + (size_t)ci * H_ * H_, nullptr, nullptr,
                  out_b + (size_t)ci * H_, x, x, nullptr, nullptr,
                  BS_, H_, H_, 1, H_, 0, stream);
            gate_w = c_gate + (size_t)ci * IM_ * H_;
            up_w   = c_up   + (size_t)ci * IM_ * H_;
            down_w = c_down + (size_t)ci * H_ * IM_;
            ln2    = c_ln2  + (size_t)ci * H_;
            ci++;
        }
        // ---- MLP (full IM width) ----
        rmsnorm768_split<<<BS_, 256, 0, stream>>>(x, ln2, Hh, Hl);
        gemm3(Hh, Hl, gate_w, nullptr, nullptr, nullptr, nullptr, nullptr,
              Gh, Gl, BS_, IM_, H_, 1, IM_, 1, stream);
        gemm3(Hh, Hl, up_w, nullptr, nullptr, nullptr, nullptr, nullptr,
              Gh, Gl, BS_, IM_, H_, 1, IM_, 2, stream);
        // down-proj: split-K=2, atomic accumulate into residual x
        gemm3(Gh, Gl, down_w, nullptr, nullptr, nullptr, nullptr, x,
              nullptr, nullptr, BS_, H_, IM_, 2, H_, 3, stream);
    }

    rmsnorm768_split<<<BS_, 256, 0, stream>>>(x, fin_ln, Hh, Hl);
    // lm_head: single launch, N = 50304 = 393 tiles
    gemm3(Hh, Hl, lm_head, nullptr, nullptr, nullptr, nullptr, (float*)d_out,
          nullptr, nullptr, BS_, V_, H_, 1, V_, 0, stream);
}